// Round 6
// baseline (363.039 us; speedup 1.0000x reference)
//
#include <hip/hip_runtime.h>

#define HW 36864            // 192*192
#define HDIM 192
#define NUNITS 8192         // 1024 windows * 8 heads
#define UPB 2               // units per block; each unit = 2 waves (half the m-range each)

typedef __fp16 h2 __attribute__((ext_vector_type(2)));

static __device__ __forceinline__ h2 pk2(float a, float b) {
    return __builtin_amdgcn_cvt_pkrtz(a, b);   // v_cvt_pkrtz_f16_f32
}
static __device__ __forceinline__ unsigned h2u(h2 x) {
    union { h2 h; unsigned u; } c; c.h = x; return c.u;
}
static __device__ __forceinline__ h2 u2h(unsigned x) {
    union { unsigned u; h2 h; } c; c.u = x; return c.h;
}

// 24-elem dot via v_dot2_f32_f16, 4 independent 3-deep chains
static __device__ __forceinline__ float rowdot(const uint4* kk, const h2* qh) {
    float d0 = __builtin_amdgcn_fdot2(u2h(kk[0].x), qh[0], 0.f, false);
    float d1 = __builtin_amdgcn_fdot2(u2h(kk[0].y), qh[1], 0.f, false);
    float d2 = __builtin_amdgcn_fdot2(u2h(kk[0].z), qh[2], 0.f, false);
    float d3 = __builtin_amdgcn_fdot2(u2h(kk[0].w), qh[3], 0.f, false);
    d0 = __builtin_amdgcn_fdot2(u2h(kk[1].x), qh[4],  d0, false);
    d1 = __builtin_amdgcn_fdot2(u2h(kk[1].y), qh[5],  d1, false);
    d2 = __builtin_amdgcn_fdot2(u2h(kk[1].z), qh[6],  d2, false);
    d3 = __builtin_amdgcn_fdot2(u2h(kk[1].w), qh[7],  d3, false);
    d0 = __builtin_amdgcn_fdot2(u2h(kk[2].x), qh[8],  d0, false);
    d1 = __builtin_amdgcn_fdot2(u2h(kk[2].y), qh[9],  d1, false);
    d2 = __builtin_amdgcn_fdot2(u2h(kk[2].z), qh[10], d2, false);
    d3 = __builtin_amdgcn_fdot2(u2h(kk[2].w), qh[11], d3, false);
    return (d0 + d1) + (d2 + d3);
}

static __device__ __forceinline__ void rowpv(const uint4* vv, h2 p2, h2* o2) {
    o2[0]  += p2 * u2h(vv[0].x);  o2[1]  += p2 * u2h(vv[0].y);
    o2[2]  += p2 * u2h(vv[0].z);  o2[3]  += p2 * u2h(vv[0].w);
    o2[4]  += p2 * u2h(vv[1].x);  o2[5]  += p2 * u2h(vv[1].y);
    o2[6]  += p2 * u2h(vv[1].z);  o2[7]  += p2 * u2h(vv[1].w);
    o2[8]  += p2 * u2h(vv[2].x);  o2[9]  += p2 * u2h(vv[2].y);
    o2[10] += p2 * u2h(vv[2].z);  o2[11] += p2 * u2h(vv[2].w);
}

__global__ __launch_bounds__(256, 6)
void attn_scatter(const float* __restrict__ x,
                  const float* __restrict__ fc,   // (8,8,2) cos/sin
                  const float* __restrict__ wgt,  // (192,192)
                  float* __restrict__ out)        // (576,192,192) pre-zeroed
{
    const int wave = threadIdx.x >> 6;
    const int lane = threadIdx.x & 63;
    const int uib  = wave >> 1;       // unit in block (0..1)
    const int half = wave & 1;        // which m-half this wave sums
    const int gid  = blockIdx.x * UPB + uib;
    const int head = gid & 7;
    const int wi   = gid >> 3;
    const int g    = wi & 3;
    const int iw   = (wi >> 2) & 15;
    const int ih   = wi >> 6;

    __shared__ __align__(16) unsigned kbuf[UPB * 64 * 12];  // f16-pair rows, post-PE k
    __shared__ __align__(16) unsigned vbuf[UPB * 64 * 12];
    __shared__ float frs[64];
    __shared__ float fis[64];
    __shared__ float ssum[UPB * 2 * 64];                    // partial softmax sums

    if (threadIdx.x < 64) {
        float2 t = ((const float2*)fc)[threadIdx.x];
        frs[threadIdx.x] = t.x;
        fis[threadIdx.x] = t.y;
    }

    // own position (query row / output position)
    const int r   = lane >> 3;
    const int col = lane & 7;
    const int h0 = ih * 12 + r;
    const int w0 = iw * 12 + col;
    int in_h = h0 + ((g & 1) ? 6 : 0); if (in_h >= HDIM) in_h = 2 * HDIM - 2 - in_h;
    int in_w = w0 + ((g & 2) ? 6 : 0); if (in_w >= HDIM) in_w = 2 * HDIM - 2 - in_w;

    // staging role: lanes 0-31 stage k rows, lanes 32-63 stage v rows
    const bool krole = (lane < 32);
    const int  srow  = half * 32 + (lane & 31);   // row this lane stages
    const int  sr    = srow >> 3;
    const int  scl   = srow & 7;
    const int  sh0 = ih * 12 + sr;
    const int  sw0 = iw * 12 + scl;
    int s_h = sh0 + ((g & 1) ? 6 : 0); if (s_h >= HDIM) s_h = 2 * HDIM - 2 - s_h;
    int s_w = sw0 + ((g & 2) ? 6 : 0); if (s_w >= HDIM) s_w = 2 * HDIM - 2 - s_w;

    const float* xh = x + (size_t)(head * 24) * HW;
    const float* xq = xh + in_h * HDIM + in_w;
    const float* xs = xh + (krole ? (size_t)192 * HW : (size_t)384 * HW) + s_h * HDIM + s_w;

    float q[24], sv[24];
#pragma unroll
    for (int dd = 0; dd < 24; ++dd) q[dd]  = xq[(size_t)dd * HW];
#pragma unroll
    for (int dd = 0; dd < 24; ++dd) sv[dd] = xs[(size_t)dd * HW];

    __syncthreads();  // frs/fis ready

    // PE on q (own row/col)
#pragma unroll
    for (int p = 0; p < 8; ++p) {
        const float frr = frs[r * 8 + p],   fir = fis[r * 8 + p];
        const float frc = frs[col * 8 + p], fic = fis[col * 8 + p];
        float a = q[3*p], b = q[3*p+1], c3 = q[3*p+2];
        float b2 = a * fir + b * frr;
        q[3*p]   = a * frr - b * fir;
        q[3*p+1] = b2 * frc - c3 * fic;
        q[3*p+2] = b2 * fic + c3 * frc;
    }
    // PE on staged k rows (k-staging lanes only; v passes through)
    if (krole) {
#pragma unroll
        for (int p = 0; p < 8; ++p) {
            const float frr = frs[sr * 8 + p],  fir = fis[sr * 8 + p];
            const float frc = frs[scl * 8 + p], fic = fis[scl * 8 + p];
            float a = sv[3*p], b = sv[3*p+1], c3 = sv[3*p+2];
            float b2 = a * fir + b * frr;
            sv[3*p]   = a * frr - b * fir;
            sv[3*p+1] = b2 * frc - c3 * fic;
            sv[3*p+2] = b2 * fic + c3 * frc;
        }
    }

    // write staged row as packed f16 pairs
    {
        unsigned* wp = (krole ? kbuf : vbuf) + (uib * 64 + srow) * 12;
#pragma unroll
        for (int j = 0; j < 12; ++j) wp[j] = h2u(pk2(sv[2*j], sv[2*j+1]));
    }

    // q -> f16 pairs, pre-scaled by 1/sqrt(24)
    h2 qh[12];
#pragma unroll
    for (int j = 0; j < 12; ++j)
        qh[j] = pk2(q[2*j] * 0.20412414523193154f, q[2*j+1] * 0.20412414523193154f);

    __syncthreads();

    float sum = 0.f;
    h2 o2[12];
#pragma unroll
    for (int j = 0; j < 12; ++j) { o2[j][0] = (__fp16)0.0f; o2[j][1] = (__fp16)0.0f; }

    const uint4* kb4 = (const uint4*)&kbuf[uib * 64 * 12];  // 3 uint4 per row
    const uint4* vb4 = (const uint4*)&vbuf[uib * 64 * 12];
    const int m0 = half * 32;

#pragma unroll 4
    for (int mm = 0; mm < 32; ++mm) {
        const int m = m0 + mm;
        uint4 kk[3];
        kk[0] = kb4[m*3]; kk[1] = kb4[m*3+1]; kk[2] = kb4[m*3+2];
        const float s = rowdot(kk, qh);
        const float p = __expf(s);
        sum += p;
        uint4 vv[3];
        vv[0] = vb4[m*3]; vv[1] = vb4[m*3+1]; vv[2] = vb4[m*3+2];
        rowpv(vv, pk2(p, p), o2);
    }

    // exchange partial sums between the unit's two waves
    ssum[(uib * 2 + half) * 64 + lane] = sum;
    __syncthreads();
    const float tot = sum + ssum[(uib * 2 + (1 - half)) * 64 + lane];

    // each wave scatters its own partial o (atomics commute)
    const int oh = h0 + ((g & 1) ? 6 : 0);
    const int ow = w0 + ((g & 2) ? 6 : 0);
    if (oh < HDIM && ow < HDIM) {
        const float sc = (1.0f / tot) / wgt[oh * HDIM + ow];
        float* ob = out + (size_t)(head * 24) * HW + oh * HDIM + ow;
#pragma unroll
        for (int j = 0; j < 12; ++j) {
            atomicAdd(&ob[(size_t)(2*j)     * HW], (float)o2[j][0] * sc);
            atomicAdd(&ob[(size_t)(2*j + 1) * HW], (float)o2[j][1] * sc);
        }
    }
}

extern "C" void kernel_launch(void* const* d_in, const int* in_sizes, int n_in,
                              void* d_out, int out_size, void* d_ws, size_t ws_size,
                              hipStream_t stream) {
    const float* x   = (const float*)d_in[0];
    const float* fc  = (const float*)d_in[1];
    const float* wgt = (const float*)d_in[2];
    float* out = (float*)d_out;

    (void)hipMemsetAsync(out, 0, (size_t)out_size * sizeof(float), stream);
    attn_scatter<<<NUNITS / UPB, 256, 0, stream>>>(x, fc, wgt, out);
}

// Round 7
// 227.557 us; speedup vs baseline: 1.5954x; 1.5954x over previous
//
#include <hip/hip_runtime.h>

#define HW 36864            // 192*192
#define HDIM 192
#define NUNITS 8192         // 1024 windows * 8 heads
#define UPB 2               // units (waves) per block
#define UDW 2688            // LDS dwords per unit
#define QO 0                // qbuf: 64 rows * 12 dw (24 f16, no pad)
#define KO 768              // kbuf: 64 rows * 12 dw
#define VTO 1536            // vbufT: 32 rows * 36 dw (72 f16: 64 data + 8 pad)
#define PO 0                // pbuf overlays qbuf+kbuf: 64 rows * 36 dw = 2304

typedef __fp16 h2  __attribute__((ext_vector_type(2)));
typedef __fp16 v8h __attribute__((ext_vector_type(8)));
typedef float  v4f __attribute__((ext_vector_type(4)));

static __device__ __forceinline__ h2 pk2(float a, float b) {
    return __builtin_amdgcn_cvt_pkrtz(a, b);   // v_cvt_pkrtz_f16_f32
}
static __device__ __forceinline__ unsigned h2u(h2 x) {
    union { h2 h; unsigned u; } c; c.h = x; return c.u;
}
static __device__ __forceinline__ v8h as_v8h(uint4 u) {
    union { uint4 u; v8h h; } c; c.u = u; return c.h;
}

__global__ __launch_bounds__(128, 3)
void attn_mfma(const float* __restrict__ x,
               const float* __restrict__ fc,   // (8,8,2) cos/sin
               const float* __restrict__ wgt,  // (192,192)
               float* __restrict__ out)        // (576,192,192) pre-zeroed
{
    __shared__ unsigned lds[UPB * UDW];
    __shared__ float frs[64], fis[64];
    __shared__ unsigned zblk[4];               // 16B of zeros (padded MFMA k-reads)

    const int wave = threadIdx.x >> 6;
    const int lane = threadIdx.x & 63;
    const int gid  = blockIdx.x * UPB + wave;
    const int head = gid & 7;
    const int wi   = gid >> 3;
    const int g    = wi & 3;
    const int iw   = (wi >> 2) & 15;
    const int ih   = wi >> 6;

    unsigned* uld = &lds[wave * UDW];

    if (threadIdx.x < 64) {
        float2 t = ((const float2*)fc)[threadIdx.x];
        frs[threadIdx.x] = t.x; fis[threadIdx.x] = t.y;
    } else if (threadIdx.x < 68) {
        zblk[threadIdx.x - 64] = 0;
    }

    // ---- phase 1: gather + PE + stage (lane owns one window position) ----
    const int r = lane >> 3, col = lane & 7;
    const int h0 = ih * 12 + r, w0 = iw * 12 + col;
    int in_h = h0 + ((g & 1) ? 6 : 0); if (in_h >= HDIM) in_h = 2 * HDIM - 2 - in_h;
    int in_w = w0 + ((g & 2) ? 6 : 0); if (in_w >= HDIM) in_w = 2 * HDIM - 2 - in_w;

    const float* xb = x + (size_t)(head * 24) * HW + in_h * HDIM + in_w;
    float q[24], k[24], v[24];
#pragma unroll
    for (int dd = 0; dd < 24; ++dd) q[dd] = xb[(size_t)dd * HW];
#pragma unroll
    for (int dd = 0; dd < 24; ++dd) k[dd] = xb[(size_t)dd * HW + (size_t)192 * HW];
#pragma unroll
    for (int dd = 0; dd < 24; ++dd) v[dd] = xb[(size_t)dd * HW + (size_t)384 * HW];

    __syncthreads();  // frs/fis/zblk ready

#pragma unroll
    for (int p = 0; p < 8; ++p) {
        const float frr = frs[r * 8 + p],   fir = fis[r * 8 + p];
        const float frc = frs[col * 8 + p], fic = fis[col * 8 + p];
        {
            float a = q[3*p], b = q[3*p+1], c3 = q[3*p+2];
            float b2 = a * fir + b * frr;
            q[3*p]   = a * frr - b * fir;
            q[3*p+1] = b2 * frc - c3 * fic;
            q[3*p+2] = b2 * fic + c3 * frc;
        }
        {
            float a = k[3*p], b = k[3*p+1], c3 = k[3*p+2];
            float b2 = a * fir + b * frr;
            k[3*p]   = a * frr - b * fir;
            k[3*p+1] = b2 * frc - c3 * fic;
            k[3*p+2] = b2 * fic + c3 * frc;
        }
    }

    // stage q (pre-scaled) and k rows: 12 uints of f16 pairs each
    {
        const float sc = 0.20412414523193154f;   // 1/sqrt(24)
        uint2* qw = (uint2*)&uld[QO + lane * 12];
        uint2* kw = (uint2*)&uld[KO + lane * 12];
#pragma unroll
        for (int j = 0; j < 3; ++j) {
            qw[2*j]   = make_uint2(h2u(pk2(q[8*j]*sc,   q[8*j+1]*sc)),
                                   h2u(pk2(q[8*j+2]*sc, q[8*j+3]*sc)));
            qw[2*j+1] = make_uint2(h2u(pk2(q[8*j+4]*sc, q[8*j+5]*sc)),
                                   h2u(pk2(q[8*j+6]*sc, q[8*j+7]*sc)));
            kw[2*j]   = make_uint2(h2u(pk2(k[8*j],   k[8*j+1])),
                                   h2u(pk2(k[8*j+2], k[8*j+3])));
            kw[2*j+1] = make_uint2(h2u(pk2(k[8*j+4], k[8*j+5])),
                                   h2u(pk2(k[8*j+6], k[8*j+7])));
        }
    }
    // stage V transposed: vbufT[d][m], rows 24..31 zero, row 24 = ones (sum trick)
    {
#pragma unroll
        for (int i = 0; i < 5; ++i) {           // zero rows 24..31 (288 dw)
            int idx = lane + i * 64;
            if (idx < 288) uld[VTO + 24 * 36 + idx] = 0;
        }
        __fp16* vt = (__fp16*)&uld[VTO];
        vt[24 * 72 + lane] = (__fp16)1.0f;      // ones row -> softmax denominators
#pragma unroll
        for (int dd = 0; dd < 24; ++dd) vt[dd * 72 + lane] = (__fp16)v[dd];
    }
    __syncthreads();   // safety: staging visible (also keeps the 2 waves loosely in step)

    // ---- phase 2: fragments ----
    const int qq = lane >> 4, l15 = lane & 15;
    v8h Qf[4], Kf[4];
#pragma unroll
    for (int t = 0; t < 4; ++t) {
        const unsigned* qa = (qq < 3) ? &uld[QO + (16*t + l15)*12 + 4*qq] : zblk;
        const unsigned* ka = (qq < 3) ? &uld[KO + (16*t + l15)*12 + 4*qq] : zblk;
        Qf[t] = as_v8h(*(const uint4*)qa);
        Kf[t] = as_v8h(*(const uint4*)ka);
    }
    v8h Vf[2][2];
#pragma unroll
    for (int dt = 0; dt < 2; ++dt)
#pragma unroll
        for (int ks = 0; ks < 2; ++ks)
            Vf[dt][ks] = as_v8h(*(const uint4*)&uld[VTO + (16*dt + l15)*36 + 16*ks + 4*qq]);

    // ---- S = Q*K^T (16 mfma), exp, P -> LDS (f16) ----
    __fp16* pb = (__fp16*)&uld[PO];
#pragma unroll
    for (int tn = 0; tn < 4; ++tn) {
#pragma unroll
        for (int tm = 0; tm < 4; ++tm) {
            v4f c = {0.f, 0.f, 0.f, 0.f};
            c = __builtin_amdgcn_mfma_f32_16x16x32_f16(Qf[tm], Kf[tn], c, 0, 0, 0);
#pragma unroll
            for (int rg = 0; rg < 4; ++rg)
                pb[(16*tm + 4*qq + rg) * 72 + 16*tn + l15] = (__fp16)__expf(c[rg]);
        }
    }

    // ---- O^T = V^T * P^T (16 mfma) ----
    v4f O[2][4];
#pragma unroll
    for (int dt = 0; dt < 2; ++dt)
#pragma unroll
        for (int lt = 0; lt < 4; ++lt)
            O[dt][lt] = (v4f){0.f, 0.f, 0.f, 0.f};
#pragma unroll
    for (int lt = 0; lt < 4; ++lt) {
#pragma unroll
        for (int ks = 0; ks < 2; ++ks) {
            v8h Pf = as_v8h(*(const uint4*)&uld[PO + (16*lt + l15)*36 + 16*ks + 4*qq]);
            O[0][lt] = __builtin_amdgcn_mfma_f32_16x16x32_f16(Vf[0][ks], Pf, O[0][lt], 0, 0, 0);
            O[1][lt] = __builtin_amdgcn_mfma_f32_16x16x32_f16(Vf[1][ks], Pf, O[1][lt], 0, 0, 0);
        }
    }

    // denominators: row d=24 (ones) lives in O[1][lt], quad 2, reg 0, lanes 32..47
    float inv[4];
#pragma unroll
    for (int lt = 0; lt < 4; ++lt)
        inv[lt] = 1.0f / __shfl(O[1][lt][0], 32 + l15, 64);

    // ---- scatter (C-layout: lane holds col l = 16*lt + l15, rows d = 16*dt + 4*qq + rg) ----
#pragma unroll
    for (int lt = 0; lt < 4; ++lt) {
        const int l  = 16*lt + l15;
        const int oh = ih * 12 + (l >> 3) + ((g & 1) ? 6 : 0);
        const int ow = iw * 12 + (l & 7)  + ((g & 2) ? 6 : 0);
        if (oh < HDIM && ow < HDIM) {
            const float sc = inv[lt] / wgt[oh * HDIM + ow];
            float* ob = out + (size_t)(head * 24) * HW + oh * HDIM + ow;
#pragma unroll
            for (int rg = 0; rg < 4; ++rg)
                atomicAdd(ob + (size_t)(4*qq + rg) * HW, O[0][lt][rg] * sc);
            if (qq < 2) {
#pragma unroll
                for (int rg = 0; rg < 4; ++rg)
                    atomicAdd(ob + (size_t)(16 + 4*qq + rg) * HW, O[1][lt][rg] * sc);
            }
        }
    }
}

extern "C" void kernel_launch(void* const* d_in, const int* in_sizes, int n_in,
                              void* d_out, int out_size, void* d_ws, size_t ws_size,
                              hipStream_t stream) {
    const float* x   = (const float*)d_in[0];
    const float* fc  = (const float*)d_in[1];
    const float* wgt = (const float*)d_in[2];
    float* out = (float*)d_out;

    (void)hipMemsetAsync(out, 0, (size_t)out_size * sizeof(float), stream);
    attn_mfma<<<NUNITS / UPB, UPB * 64, 0, stream>>>(x, fc, wgt, out);
}